// Round 5
// baseline (852.055 us; speedup 1.0000x reference)
//
#include <hip/hip_runtime.h>
#include <hip/hip_bf16.h>
#include <math.h>

#define HDIM 64
#define NN   100000
#define NE   1600000
#define TEMP 30.0f
#define LNEPS 1e-5f

// bucketing: G=64 nodes per bucket
#define GSH  6
#define GSZ  64
#define NB   1563          // ceil(NN/64)
#define NSH  8             // XCD shards
#define NSB  (NSH * NB)    // 12504 counters
#define E2   782           // edges per scatter block (2048 blocks)

typedef __attribute__((ext_vector_type(8))) short bf16x8;
typedef __attribute__((ext_vector_type(4))) float f32x4;

__device__ __forceinline__ short f2bf(float f) {
    __hip_bfloat16 b = __float2bfloat16(f);
    short s; __builtin_memcpy(&s, &b, 2); return s;
}
__device__ __forceinline__ unsigned pk2(float lo, float hi) {
    return (unsigned)(unsigned short)f2bf(lo) | ((unsigned)(unsigned short)f2bf(hi) << 16);
}
__device__ __forceinline__ float bf2f(unsigned u) {
    union { unsigned u; float f; } c; c.u = u << 16; return c.f;
}
__device__ __forceinline__ float sigmoidf_(float z) { return 1.0f / (1.0f + __expf(-z)); }

// ============ Pre kernel: per-NODE factorization of edge GEMM1 ============
// Pt[n] = h[n] @ We1_top + be1 ; Pb[n] = h[n] @ We1_bot   (bf16 rows, 128 B)
extern "C" __global__ void __launch_bounds__(256, 2)
pre_kernel(const float* __restrict__ h,
           const float* __restrict__ We1, const float* __restrict__ be1,
           unsigned short* __restrict__ Pt, unsigned short* __restrict__ Pb)
{
    __shared__ float fx[4][1024];
    const int tid  = threadIdx.x;
    const int wib  = tid >> 6;
    const int lane = tid & 63;
    const int e = lane & 15, g = lane >> 4;
    float* fb = &fx[wib][0];
    const int se = ((e & 1) << 4) | ((e >> 1) & 3);

    bf16x8 At[4][2], Ab[4][2];
    f32x4 b1r[4];
    #pragma unroll
    for (int t = 0; t < 4; ++t) {
        #pragma unroll
        for (int ks = 0; ks < 2; ++ks) {
            bf16x8 a, b;
            #pragma unroll
            for (int j = 0; j < 8; ++j) {
                a[j] = f2bf(We1[(32 * ks + 8 * g + j) * 64 + 16 * t + e]);
                b[j] = f2bf(We1[(64 + 32 * ks + 8 * g + j) * 64 + 16 * t + e]);
            }
            At[t][ks] = a; Ab[t][ks] = b;
        }
        #pragma unroll
        for (int r = 0; r < 4; ++r) b1r[t][r] = be1[16 * t + 4 * g + r];
    }

    const int gwid = blockIdx.x * 4 + wib;
    const int nw   = gridDim.x * 4;

    for (int tile = gwid; tile < NN / 16; tile += nw) {
        const int node = tile * 16 + e;

        bf16x8 B[2];
        #pragma unroll
        for (int ks = 0; ks < 2; ++ks) {
            const float4* p = (const float4*)(h + (size_t)node * 64 + ks * 32 + 8 * g);
            const float4 f0 = p[0], f1 = p[1];
            bf16x8 b;
            b[0] = f2bf(f0.x); b[1] = f2bf(f0.y); b[2] = f2bf(f0.z); b[3] = f2bf(f0.w);
            b[4] = f2bf(f1.x); b[5] = f2bf(f1.y); b[6] = f2bf(f1.z); b[7] = f2bf(f1.w);
            B[ks] = b;
        }

        f32x4 aT[4], aB[4];
        #pragma unroll
        for (int t = 0; t < 4; ++t) {
            aT[t] = b1r[t];
            aB[t] = (f32x4){0.f, 0.f, 0.f, 0.f};
            #pragma unroll
            for (int ks = 0; ks < 2; ++ks) {
                aT[t] = __builtin_amdgcn_mfma_f32_16x16x32_bf16(At[t][ks], B[ks], aT[t], 0, 0, 0);
                aB[t] = __builtin_amdgcn_mfma_f32_16x16x32_bf16(Ab[t][ks], B[ks], aB[t], 0, 0, 0);
            }
        }

        #pragma unroll
        for (int t = 0; t < 4; ++t)
            #pragma unroll
            for (int r = 0; r < 4; ++r)
                fb[e * 64 + ((16 * t + 4 * g + r) ^ se)] = aT[t][r];
        #pragma unroll
        for (int q = 0; q < 2; ++q) {
            const int row = q * 8 + (lane >> 3);
            const int sr  = ((row & 1) << 4) | ((row >> 1) & 3);
            const int c0  = (lane & 7) * 8;
            uint4 o;
            o.x = pk2(fb[row * 64 + ((c0 + 0) ^ sr)], fb[row * 64 + ((c0 + 1) ^ sr)]);
            o.y = pk2(fb[row * 64 + ((c0 + 2) ^ sr)], fb[row * 64 + ((c0 + 3) ^ sr)]);
            o.z = pk2(fb[row * 64 + ((c0 + 4) ^ sr)], fb[row * 64 + ((c0 + 5) ^ sr)]);
            o.w = pk2(fb[row * 64 + ((c0 + 6) ^ sr)], fb[row * 64 + ((c0 + 7) ^ sr)]);
            *(uint4*)((char*)Pt + (size_t)tile * 2048 + q * 1024 + lane * 16) = o;
        }

        #pragma unroll
        for (int t = 0; t < 4; ++t)
            #pragma unroll
            for (int r = 0; r < 4; ++r)
                fb[e * 64 + ((16 * t + 4 * g + r) ^ se)] = aB[t][r];
        #pragma unroll
        for (int q = 0; q < 2; ++q) {
            const int row = q * 8 + (lane >> 3);
            const int sr  = ((row & 1) << 4) | ((row >> 1) & 3);
            const int c0  = (lane & 7) * 8;
            uint4 o;
            o.x = pk2(fb[row * 64 + ((c0 + 0) ^ sr)], fb[row * 64 + ((c0 + 1) ^ sr)]);
            o.y = pk2(fb[row * 64 + ((c0 + 2) ^ sr)], fb[row * 64 + ((c0 + 3) ^ sr)]);
            o.z = pk2(fb[row * 64 + ((c0 + 4) ^ sr)], fb[row * 64 + ((c0 + 5) ^ sr)]);
            o.w = pk2(fb[row * 64 + ((c0 + 6) ^ sr)], fb[row * 64 + ((c0 + 7) ^ sr)]);
            *(uint4*)((char*)Pb + (size_t)tile * 2048 + q * 1024 + lane * 16) = o;
        }
    }
}

// ============ Bucketing: shard-private histogram / scan / scatter ============
// shard = blockIdx & 7 (round-robins XCDs) -> appends to a (shard,bucket)
// frontier come from ONE XCD -> 4B writes merge to full lines in that L2.
extern "C" __global__ void __launch_bounds__(256)
hist2_kernel(const int* __restrict__ ei, int* __restrict__ cnt2)
{
    const int b  = blockIdx.x;                   // grid must be 2048
    const int i0 = b * E2;
    const int i1 = (i0 + E2 < NE) ? i0 + E2 : NE;
    const int sh = (b & (NSH - 1)) * NB;
    for (int i = i0 + threadIdx.x; i < i1; i += 256)
        atomicAdd(&cnt2[sh + (ei[NE + i] >> GSH)], 1);
}

extern "C" __global__ void __launch_bounds__(1024)
scan2b_kernel(const int* __restrict__ cnt2, int* __restrict__ off2, int* __restrict__ cur2)
{
    __shared__ int part[1024];
    const int t = threadIdx.x;
    #define SCK 13                                // 1024*13 >= NSB
    int vals[SCK];
    int s = 0;
    #pragma unroll
    for (int j = 0; j < SCK; ++j) {
        const int idx = t * SCK + j;
        vals[j] = (idx < NSB) ? cnt2[idx] : 0;
        s += vals[j];
    }
    part[t] = s;
    __syncthreads();
    for (int off = 1; off < 1024; off <<= 1) {
        const int u = (t >= off) ? part[t - off] : 0;
        __syncthreads();
        part[t] += u;
        __syncthreads();
    }
    int run = part[t] - s;
    #pragma unroll
    for (int j = 0; j < SCK; ++j) {
        const int idx = t * SCK + j;
        if (idx < NSB) { off2[idx] = run; cur2[idx] = run; run += vals[j]; }
    }
}

extern "C" __global__ void __launch_bounds__(256)
scatter2_kernel(const int* __restrict__ ei, int* __restrict__ cur2,
                unsigned* __restrict__ sedge)
{
    const int b  = blockIdx.x;                   // grid must be 2048
    const int i0 = b * E2;
    const int i1 = (i0 + E2 < NE) ? i0 + E2 : NE;
    const int sh = (b & (NSH - 1)) * NB;
    for (int i = i0 + threadIdx.x; i < i1; i += 256) {
        const int s = ei[i];
        const int d = ei[NE + i];
        const int pos = atomicAdd(&cur2[sh + (d >> GSH)], 1);
        sedge[pos] = (unsigned)s | ((unsigned)(d & (GSZ - 1)) << 17);
    }
}

// ============ Edge kernel (bucketed): GEMM2 + gate + LDS row accumulation ====
// One block per 64-node bucket. Edges (unordered) accumulate into LDS
// acc[64][64] via ds_add_f32 (2-way banks); final rows written dense,
// non-atomic. Pt/x dst-gathers are bucket-local (L1/L2 hot).
extern "C" __global__ void __launch_bounds__(256, 2)
edge_bucket_kernel(const unsigned short* __restrict__ Pt, const unsigned short* __restrict__ Pb,
                   const float* __restrict__ x, const unsigned* __restrict__ sedge,
                   const int* __restrict__ off2, const int* __restrict__ cnt2,
                   const float* __restrict__ We2, const float* __restrict__ be2,
                   const float* __restrict__ Winf, const float* __restrict__ binf,
                   float* __restrict__ mi)
{
    __shared__ float acc[GSZ * 64];     // 16 KB
    __shared__ float fx[4][1024];       // 16 KB
    const int tid  = threadIdx.x;
    const int wib  = tid >> 6;
    const int lane = tid & 63;
    const int e = lane & 15, g = lane >> 4;
    float* fb = &fx[wib][0];
    const int se = ((e & 1) << 4) | ((e >> 1) & 3);
    const int b = blockIdx.x;

    bf16x8 A2[4][2];
    f32x4 b2r[4], wir[4];
    #pragma unroll
    for (int t = 0; t < 4; ++t) {
        #pragma unroll
        for (int ks = 0; ks < 2; ++ks) {
            bf16x8 a;
            #pragma unroll
            for (int j = 0; j < 8; ++j)
                a[j] = f2bf(We2[(32 * ks + 8 * g + j) * 64 + 16 * t + e]);
            A2[t][ks] = a;
        }
        #pragma unroll
        for (int r = 0; r < 4; ++r) {
            b2r[t][r] = be2[16 * t + 4 * g + r];
            wir[t][r] = Winf[16 * t + 4 * g + r];
        }
    }
    const float binf0 = binf[0];

    for (int i = tid; i < GSZ * 64; i += 256) acc[i] = 0.f;
    __syncthreads();

    for (int s = 0; s < NSH; ++s) {
        const int segBase = off2[s * NB + b];
        const int segEnd  = segBase + cnt2[s * NB + b];
        // wave wib takes every 4th 16-edge tile of this segment
        for (int t0 = segBase + 16 * wib; t0 < segEnd; t0 += 64) {
            int eid = t0 + e;
            const bool valid = (eid < segEnd);
            if (!valid) eid = segEnd - 1;
            const unsigned pkw = sedge[eid];
            const int sN = pkw & 0x1FFFF;
            const int dN = (b << GSH) | ((pkw >> 17) & (GSZ - 1));

            const float dx = x[dN * 3 + 0] - x[sN * 3 + 0];
            const float dy = x[dN * 3 + 1] - x[sN * 3 + 1];
            const float dz = x[dN * 3 + 2] - x[sN * 3 + 2];
            const float dsq = dx * dx + dy * dy + dz * dz;
            const float edis = sigmoidf_(TEMP / (sqrtf(dsq) + 1e-8f));

            // B2 frags: relu(Pt[dst] + Pb[src]) on k=32ks+8g+{0..7}
            bf16x8 B2[2];
            #pragma unroll
            for (int ks = 0; ks < 2; ++ks) {
                const uint4 ut = *(const uint4*)(Pt + (size_t)dN * 64 + 32 * ks + 8 * g);
                const uint4 ub = *(const uint4*)(Pb + (size_t)sN * 64 + 32 * ks + 8 * g);
                bf16x8 bb;
                unsigned tw, bw;
                tw = ut.x; bw = ub.x;
                bb[0] = f2bf(fmaxf(bf2f(tw & 0xffffu) + bf2f(bw & 0xffffu), 0.f));
                bb[1] = f2bf(fmaxf(bf2f(tw >> 16)     + bf2f(bw >> 16),     0.f));
                tw = ut.y; bw = ub.y;
                bb[2] = f2bf(fmaxf(bf2f(tw & 0xffffu) + bf2f(bw & 0xffffu), 0.f));
                bb[3] = f2bf(fmaxf(bf2f(tw >> 16)     + bf2f(bw >> 16),     0.f));
                tw = ut.z; bw = ub.z;
                bb[4] = f2bf(fmaxf(bf2f(tw & 0xffffu) + bf2f(bw & 0xffffu), 0.f));
                bb[5] = f2bf(fmaxf(bf2f(tw >> 16)     + bf2f(bw >> 16),     0.f));
                tw = ut.w; bw = ub.w;
                bb[6] = f2bf(fmaxf(bf2f(tw & 0xffffu) + bf2f(bw & 0xffffu), 0.f));
                bb[7] = f2bf(fmaxf(bf2f(tw >> 16)     + bf2f(bw >> 16),     0.f));
                B2[ks] = bb;
            }

            f32x4 acc2[4];
            #pragma unroll
            for (int t = 0; t < 4; ++t) {
                acc2[t] = b2r[t];
                #pragma unroll
                for (int ks = 0; ks < 2; ++ks)
                    acc2[t] = __builtin_amdgcn_mfma_f32_16x16x32_bf16(A2[t][ks], B2[ks], acc2[t], 0, 0, 0);
            }

            float m[4][4];
            float p = 0.f;
            #pragma unroll
            for (int t = 0; t < 4; ++t)
                #pragma unroll
                for (int r = 0; r < 4; ++r) {
                    m[t][r] = fmaxf(acc2[t][r], 0.f);
                    p = fmaf(m[t][r], wir[t][r], p);
                }
            p += __shfl_xor(p, 16);
            p += __shfl_xor(p, 32);
            float w = sigmoidf_((p + binf0) * edis);
            if (!valid) w = 0.f;   // clamped tail lanes contribute zero

            // transpose m*w through per-wave LDS to [edge][channel]
            #pragma unroll
            for (int t = 0; t < 4; ++t)
                #pragma unroll
                for (int r = 0; r < 4; ++r)
                    fb[e * 64 + ((16 * t + 4 * g + r) ^ se)] = m[t][r] * w;

            // one ds_add row-instruction per edge (banks 2-way: free)
            #pragma unroll
            for (int i2 = 0; i2 < 16; ++i2) {
                const unsigned pe = (unsigned)__builtin_amdgcn_readlane((int)pkw, i2);
                const int row = (pe >> 17) & (GSZ - 1);
                const int si = ((i2 & 1) << 4) | ((i2 >> 1) & 3);
                atomicAdd(&acc[row * 64 + lane], fb[i2 * 64 + (lane ^ si)]);
            }
        }
    }

    __syncthreads();
    const int node0 = b << GSH;
    const int nrem  = NN - node0;
    const int nfl   = ((nrem < GSZ) ? nrem : GSZ) * 64;
    for (int i = tid; i < nfl; i += 256)
        mi[(size_t)node0 * 64 + i] = acc[i];
}

// ============ Edge kernel (unsorted fallback, small-ws path) ============
extern "C" __global__ void __launch_bounds__(256, 2)
edge_kernel_unsorted(const unsigned short* __restrict__ Pt, const unsigned short* __restrict__ Pb,
                     const float* __restrict__ x, const int* __restrict__ ei,
                     const float* __restrict__ We2, const float* __restrict__ be2,
                     const float* __restrict__ Winf, const float* __restrict__ binf,
                     float* __restrict__ mi)
{
    __shared__ float fx[4][1024];
    const int tid  = threadIdx.x;
    const int wib  = tid >> 6;
    const int lane = tid & 63;
    const int e = lane & 15, g = lane >> 4;
    float* fb = &fx[wib][0];
    const int se = ((e & 1) << 4) | ((e >> 1) & 3);

    bf16x8 A2[4][2];
    f32x4 b2r[4], wir[4];
    #pragma unroll
    for (int t = 0; t < 4; ++t) {
        #pragma unroll
        for (int ks = 0; ks < 2; ++ks) {
            bf16x8 a;
            #pragma unroll
            for (int j = 0; j < 8; ++j)
                a[j] = f2bf(We2[(32 * ks + 8 * g + j) * 64 + 16 * t + e]);
            A2[t][ks] = a;
        }
        #pragma unroll
        for (int r = 0; r < 4; ++r) {
            b2r[t][r] = be2[16 * t + 4 * g + r];
            wir[t][r] = Winf[16 * t + 4 * g + r];
        }
    }
    const float binf0 = binf[0];

    const int gwid = blockIdx.x * 4 + wib;
    const int nw   = gridDim.x * 4;

    for (int tile = gwid; tile < NE / 16; tile += nw) {
        const int eid = tile * 16 + e;
        const int sN = ei[eid];
        const int dN = ei[NE + eid];

        const float dx = x[dN * 3 + 0] - x[sN * 3 + 0];
        const float dy = x[dN * 3 + 1] - x[sN * 3 + 1];
        const float dz = x[dN * 3 + 2] - x[sN * 3 + 2];
        const float dsq = dx * dx + dy * dy + dz * dz;
        const float edis = sigmoidf_(TEMP / (sqrtf(dsq) + 1e-8f));

        bf16x8 B2[2];
        #pragma unroll
        for (int ks = 0; ks < 2; ++ks) {
            const uint4 ut = *(const uint4*)(Pt + (size_t)dN * 64 + 32 * ks + 8 * g);
            const uint4 ub = *(const uint4*)(Pb + (size_t)sN * 64 + 32 * ks + 8 * g);
            bf16x8 bb;
            unsigned tw, bw;
            tw = ut.x; bw = ub.x;
            bb[0] = f2bf(fmaxf(bf2f(tw & 0xffffu) + bf2f(bw & 0xffffu), 0.f));
            bb[1] = f2bf(fmaxf(bf2f(tw >> 16)     + bf2f(bw >> 16),     0.f));
            tw = ut.y; bw = ub.y;
            bb[2] = f2bf(fmaxf(bf2f(tw & 0xffffu) + bf2f(bw & 0xffffu), 0.f));
            bb[3] = f2bf(fmaxf(bf2f(tw >> 16)     + bf2f(bw >> 16),     0.f));
            tw = ut.z; bw = ub.z;
            bb[4] = f2bf(fmaxf(bf2f(tw & 0xffffu) + bf2f(bw & 0xffffu), 0.f));
            bb[5] = f2bf(fmaxf(bf2f(tw >> 16)     + bf2f(bw >> 16),     0.f));
            tw = ut.w; bw = ub.w;
            bb[6] = f2bf(fmaxf(bf2f(tw & 0xffffu) + bf2f(bw & 0xffffu), 0.f));
            bb[7] = f2bf(fmaxf(bf2f(tw >> 16)     + bf2f(bw >> 16),     0.f));
            B2[ks] = bb;
        }

        f32x4 acc2[4];
        #pragma unroll
        for (int t = 0; t < 4; ++t) {
            acc2[t] = b2r[t];
            #pragma unroll
            for (int ks = 0; ks < 2; ++ks)
                acc2[t] = __builtin_amdgcn_mfma_f32_16x16x32_bf16(A2[t][ks], B2[ks], acc2[t], 0, 0, 0);
        }

        float m[4][4];
        float p = 0.f;
        #pragma unroll
        for (int t = 0; t < 4; ++t)
            #pragma unroll
            for (int r = 0; r < 4; ++r) {
                m[t][r] = fmaxf(acc2[t][r], 0.f);
                p = fmaf(m[t][r], wir[t][r], p);
            }
        p += __shfl_xor(p, 16);
        p += __shfl_xor(p, 32);
        const float w = sigmoidf_((p + binf0) * edis);

        #pragma unroll
        for (int t = 0; t < 4; ++t)
            #pragma unroll
            for (int r = 0; r < 4; ++r)
                fb[e * 64 + ((16 * t + 4 * g + r) ^ se)] = m[t][r] * w;

        #pragma unroll
        for (int i = 0; i < 16; ++i) {
            const int row = __shfl(dN, i);
            const int si = ((i & 1) << 4) | ((i >> 1) & 3);
            const float v = fb[i * 64 + (lane ^ si)];
            atomicAdd(mi + (size_t)row * 64 + lane, v);
        }
    }
}

// ============ Node kernel: same B2B MFMA + residual + LayerNorm =============
extern "C" __global__ void __launch_bounds__(256, 2)
node_kernel(const float* __restrict__ h, const float* __restrict__ mi_,
            const float* __restrict__ Wn1, const float* __restrict__ bn1,
            const float* __restrict__ Wn2, const float* __restrict__ bn2,
            const float* __restrict__ lng, const float* __restrict__ lnb,
            float* __restrict__ out)
{
    __shared__ unsigned xlds[4][16 * 32];
    const int tid  = threadIdx.x;
    const int wib  = tid >> 6;
    const int lane = tid & 63;
    const int e = lane & 15, g = lane >> 4;
    unsigned* tb = &xlds[wib][0];
    const int sw = (e & 7) << 2;

    bf16x8 A1[4][4], A2[4][2];
    f32x4 b1r[4], b2r[4], gr[4], br[4];
    #pragma unroll
    for (int t = 0; t < 4; ++t) {
        #pragma unroll
        for (int ks = 0; ks < 4; ++ks) {
            bf16x8 a;
            #pragma unroll
            for (int j = 0; j < 8; ++j)
                a[j] = f2bf(Wn1[(32 * ks + 8 * g + j) * 64 + 16 * t + e]);
            A1[t][ks] = a;
        }
        #pragma unroll
        for (int ks = 0; ks < 2; ++ks) {
            bf16x8 a;
            #pragma unroll
            for (int j = 0; j < 8; ++j)
                a[j] = f2bf(Wn2[(32 * ks + 8 * g + j) * 64 + 16 * t + e]);
            A2[t][ks] = a;
        }
        #pragma unroll
        for (int r = 0; r < 4; ++r) {
            b1r[t][r] = bn1[16 * t + 4 * g + r];
            b2r[t][r] = bn2[16 * t + 4 * g + r];
            gr[t][r]  = lng[16 * t + 4 * g + r];
            br[t][r]  = lnb[16 * t + 4 * g + r];
        }
    }

    const int gwid = blockIdx.x * 4 + wib;
    const int nw   = gridDim.x * 4;

    for (int tile = gwid; tile < NN / 16; tile += nw) {
        const int node = tile * 16 + e;

        bf16x8 B1[4];
        #pragma unroll
        for (int ks = 0; ks < 4; ++ks) {
            const float* srcp = (ks < 2) ? mi_ : h;
            const float4* p = (const float4*)(srcp + (size_t)node * 64 + (ks & 1) * 32 + 8 * g);
            const float4 f0 = p[0], f1 = p[1];
            bf16x8 b;
            b[0] = f2bf(f0.x); b[1] = f2bf(f0.y); b[2] = f2bf(f0.z); b[3] = f2bf(f0.w);
            b[4] = f2bf(f1.x); b[5] = f2bf(f1.y); b[6] = f2bf(f1.z); b[7] = f2bf(f1.w);
            B1[ks] = b;
        }

        f32x4 acc1[4];
        #pragma unroll
        for (int t = 0; t < 4; ++t) {
            acc1[t] = b1r[t];
            #pragma unroll
            for (int ks = 0; ks < 4; ++ks)
                acc1[t] = __builtin_amdgcn_mfma_f32_16x16x32_bf16(A1[t][ks], B1[ks], acc1[t], 0, 0, 0);
        }

        #pragma unroll
        for (int t = 0; t < 4; ++t) {
            const float r0 = fmaxf(acc1[t][0], 0.f), r1 = fmaxf(acc1[t][1], 0.f);
            const float r2 = fmaxf(acc1[t][2], 0.f), r3 = fmaxf(acc1[t][3], 0.f);
            tb[e * 32 + ((8 * t + 2 * g + 0) ^ sw)] = pk2(r0, r1);
            tb[e * 32 + ((8 * t + 2 * g + 1) ^ sw)] = pk2(r2, r3);
        }
        bf16x8 B2[2];
        #pragma unroll
        for (int ks = 0; ks < 2; ++ks) {
            union { uint4 u; bf16x8 b; } cvt;
            cvt.u = *(const uint4*)&tb[e * 32 + ((16 * ks + 4 * g) ^ sw)];
            B2[ks] = cvt.b;
        }

        f32x4 acc2[4];
        #pragma unroll
        for (int t = 0; t < 4; ++t) {
            acc2[t] = b2r[t];
            #pragma unroll
            for (int ks = 0; ks < 2; ++ks)
                acc2[t] = __builtin_amdgcn_mfma_f32_16x16x32_bf16(A2[t][ks], B2[ks], acc2[t], 0, 0, 0);
        }

        float z[4][4];
        float s1 = 0.f, s2 = 0.f;
        #pragma unroll
        for (int t = 0; t < 4; ++t) {
            const float4 hres = *(const float4*)(h + (size_t)node * 64 + 16 * t + 4 * g);
            #pragma unroll
            for (int r = 0; r < 4; ++r) {
                z[t][r] = acc2[t][r] + hres[r];
                s1 += z[t][r];
                s2 = fmaf(z[t][r], z[t][r], s2);
            }
        }
        s1 += __shfl_xor(s1, 16); s1 += __shfl_xor(s1, 32);
        s2 += __shfl_xor(s2, 16); s2 += __shfl_xor(s2, 32);
        const float mu   = s1 * (1.0f / 64.0f);
        const float var  = s2 * (1.0f / 64.0f) - mu * mu;
        const float rstd = rsqrtf(var + LNEPS);

        #pragma unroll
        for (int t = 0; t < 4; ++t) {
            float4 o;
            #pragma unroll
            for (int r = 0; r < 4; ++r)
                o[r] = (z[t][r] - mu) * rstd * gr[t][r] + br[t][r];
            *(float4*)(out + (size_t)node * 64 + 16 * t + 4 * g) = o;
        }
    }
}

extern "C" void kernel_launch(void* const* d_in, const int* in_sizes, int n_in,
                              void* d_out, int out_size, void* d_ws, size_t ws_size,
                              hipStream_t stream)
{
    const float* h    = (const float*)d_in[0];
    const float* x    = (const float*)d_in[1];
    const int*   ei   = (const int*)d_in[2];
    const float* We1  = (const float*)d_in[3];
    const float* be1  = (const float*)d_in[4];
    const float* We2  = (const float*)d_in[5];
    const float* be2  = (const float*)d_in[6];
    const float* Winf = (const float*)d_in[7];
    const float* binf = (const float*)d_in[8];
    const float* Wn1  = (const float*)d_in[9];
    const float* bn1  = (const float*)d_in[10];
    const float* Wn2  = (const float*)d_in[11];
    const float* bn2  = (const float*)d_in[12];
    const float* lng  = (const float*)d_in[13];
    const float* lnb  = (const float*)d_in[14];
    float* out = (float*)d_out;

    const size_t mi_bytes = (size_t)NN * HDIM * sizeof(float);          // 25.6 MB
    const size_t p_bytes  = (size_t)NN * HDIM * sizeof(unsigned short); // 12.8 MB
    const size_t se_bytes = (size_t)NE * sizeof(unsigned);              //  6.4 MB
    const size_t c_bytes  = (size_t)NSB * sizeof(int);                  // ~50 KB

    const size_t need_bucketed = mi_bytes + 2 * p_bytes + se_bytes + 3 * c_bytes;

    if (ws_size >= need_bucketed) {
        char* ws = (char*)d_ws;
        float*          mi    = (float*)ws;              ws += mi_bytes;
        unsigned short* Pt    = (unsigned short*)ws;     ws += p_bytes;
        unsigned short* Pb    = (unsigned short*)ws;     ws += p_bytes;
        unsigned*       sedge = (unsigned*)ws;           ws += se_bytes;
        int*            cnt2  = (int*)ws;                ws += c_bytes;
        int*            off2  = (int*)ws;                ws += c_bytes;
        int*            cur2  = (int*)ws;

        hipMemsetAsync(cnt2, 0, c_bytes, stream);
        hipMemcpyAsync(out + (size_t)NN * HDIM, x, (size_t)NN * 3 * sizeof(float),
                       hipMemcpyDeviceToDevice, stream);

        hist2_kernel<<<2048, 256, 0, stream>>>(ei, cnt2);
        scan2b_kernel<<<1, 1024, 0, stream>>>(cnt2, off2, cur2);
        scatter2_kernel<<<2048, 256, 0, stream>>>(ei, cur2, sedge);
        pre_kernel<<<512, 256, 0, stream>>>(h, We1, be1, Pt, Pb);
        edge_bucket_kernel<<<NB, 256, 0, stream>>>(Pt, Pb, x, sedge, off2, cnt2,
                                                   We2, be2, Winf, binf, mi);
        node_kernel<<<512, 256, 0, stream>>>(h, mi, Wn1, bn1, Wn2, bn2, lng, lnb, out);
    } else {
        float* mi;
        unsigned short* Pt;
        unsigned short* Pb;
        if (ws_size >= mi_bytes + 2 * p_bytes) {
            mi = (float*)d_ws;
            Pt = (unsigned short*)((char*)d_ws + mi_bytes);
            Pb = (unsigned short*)((char*)d_ws + mi_bytes + p_bytes);
        } else {
            mi = out;
            Pt = (unsigned short*)d_ws;
            Pb = (unsigned short*)((char*)d_ws + p_bytes);
        }

        hipMemsetAsync(mi, 0, mi_bytes, stream);
        hipMemcpyAsync(out + (size_t)NN * HDIM, x, (size_t)NN * 3 * sizeof(float),
                       hipMemcpyDeviceToDevice, stream);

        pre_kernel<<<512, 256, 0, stream>>>(h, We1, be1, Pt, Pb);
        edge_kernel_unsorted<<<2048, 256, 0, stream>>>(Pt, Pb, x, ei, We2, be2, Winf, binf, mi);
        node_kernel<<<512, 256, 0, stream>>>(h, mi, Wn1, bn1, Wn2, bn2, lng, lnb, out);
    }
}

// Round 6
// 316.064 us; speedup vs baseline: 2.6958x; 2.6958x over previous
//
#include <hip/hip_runtime.h>
#include <hip/hip_bf16.h>
#include <math.h>

#define HDIM 64
#define NN   100000
#define NE   1600000
#define TEMP 30.0f
#define LNEPS 1e-5f

// bucketing: 64 nodes per bucket, 8 XCD shards
#define GSH  6
#define GSZ  64
#define NB   1563          // ceil(NN/64)
#define NSH  8
#define NSB  (NSH * NB)    // 12504 counters (bucket-major, shard-minor)
#define E2   782           // edges per hist/scatter block (2048 blocks)
#define SCANB 13           // ceil(NSB/1024)

typedef __attribute__((ext_vector_type(8))) short bf16x8;
typedef __attribute__((ext_vector_type(4))) float f32x4;

__device__ __forceinline__ short f2bf(float f) {
    __hip_bfloat16 b = __float2bfloat16(f);
    short s; __builtin_memcpy(&s, &b, 2); return s;
}
__device__ __forceinline__ unsigned pk2(float lo, float hi) {
    return (unsigned)(unsigned short)f2bf(lo) | ((unsigned)(unsigned short)f2bf(hi) << 16);
}
__device__ __forceinline__ float bf2f(unsigned u) {
    union { unsigned u; float f; } c; c.u = u << 16; return c.f;
}
__device__ __forceinline__ float sigmoidf_(float z) { return 1.0f / (1.0f + __expf(-z)); }

// ============ Pre kernel: per-NODE factorization of edge GEMM1 ============
// Pt[n] = h[n] @ We1_top + be1 ; Pb[n] = h[n] @ We1_bot   (bf16 rows, 128 B)
extern "C" __global__ void __launch_bounds__(256, 2)
pre_kernel(const float* __restrict__ h,
           const float* __restrict__ We1, const float* __restrict__ be1,
           unsigned short* __restrict__ Pt, unsigned short* __restrict__ Pb)
{
    __shared__ float fx[4][1024];
    const int tid  = threadIdx.x;
    const int wib  = tid >> 6;
    const int lane = tid & 63;
    const int e = lane & 15, g = lane >> 4;
    float* fb = &fx[wib][0];
    const int se = ((e & 1) << 4) | ((e >> 1) & 3);

    bf16x8 At[4][2], Ab[4][2];
    f32x4 b1r[4];
    #pragma unroll
    for (int t = 0; t < 4; ++t) {
        #pragma unroll
        for (int ks = 0; ks < 2; ++ks) {
            bf16x8 a, b;
            #pragma unroll
            for (int j = 0; j < 8; ++j) {
                a[j] = f2bf(We1[(32 * ks + 8 * g + j) * 64 + 16 * t + e]);
                b[j] = f2bf(We1[(64 + 32 * ks + 8 * g + j) * 64 + 16 * t + e]);
            }
            At[t][ks] = a; Ab[t][ks] = b;
        }
        #pragma unroll
        for (int r = 0; r < 4; ++r) b1r[t][r] = be1[16 * t + 4 * g + r];
    }

    const int gwid = blockIdx.x * 4 + wib;
    const int nw   = gridDim.x * 4;

    for (int tile = gwid; tile < NN / 16; tile += nw) {
        const int node = tile * 16 + e;

        bf16x8 B[2];
        #pragma unroll
        for (int ks = 0; ks < 2; ++ks) {
            const float4* p = (const float4*)(h + (size_t)node * 64 + ks * 32 + 8 * g);
            const float4 f0 = p[0], f1 = p[1];
            bf16x8 b;
            b[0] = f2bf(f0.x); b[1] = f2bf(f0.y); b[2] = f2bf(f0.z); b[3] = f2bf(f0.w);
            b[4] = f2bf(f1.x); b[5] = f2bf(f1.y); b[6] = f2bf(f1.z); b[7] = f2bf(f1.w);
            B[ks] = b;
        }

        f32x4 aT[4], aB[4];
        #pragma unroll
        for (int t = 0; t < 4; ++t) {
            aT[t] = b1r[t];
            aB[t] = (f32x4){0.f, 0.f, 0.f, 0.f};
            #pragma unroll
            for (int ks = 0; ks < 2; ++ks) {
                aT[t] = __builtin_amdgcn_mfma_f32_16x16x32_bf16(At[t][ks], B[ks], aT[t], 0, 0, 0);
                aB[t] = __builtin_amdgcn_mfma_f32_16x16x32_bf16(Ab[t][ks], B[ks], aB[t], 0, 0, 0);
            }
        }

        #pragma unroll
        for (int t = 0; t < 4; ++t)
            #pragma unroll
            for (int r = 0; r < 4; ++r)
                fb[e * 64 + ((16 * t + 4 * g + r) ^ se)] = aT[t][r];
        #pragma unroll
        for (int q = 0; q < 2; ++q) {
            const int row = q * 8 + (lane >> 3);
            const int sr  = ((row & 1) << 4) | ((row >> 1) & 3);
            const int c0  = (lane & 7) * 8;
            uint4 o;
            o.x = pk2(fb[row * 64 + ((c0 + 0) ^ sr)], fb[row * 64 + ((c0 + 1) ^ sr)]);
            o.y = pk2(fb[row * 64 + ((c0 + 2) ^ sr)], fb[row * 64 + ((c0 + 3) ^ sr)]);
            o.z = pk2(fb[row * 64 + ((c0 + 4) ^ sr)], fb[row * 64 + ((c0 + 5) ^ sr)]);
            o.w = pk2(fb[row * 64 + ((c0 + 6) ^ sr)], fb[row * 64 + ((c0 + 7) ^ sr)]);
            *(uint4*)((char*)Pt + (size_t)tile * 2048 + q * 1024 + lane * 16) = o;
        }

        #pragma unroll
        for (int t = 0; t < 4; ++t)
            #pragma unroll
            for (int r = 0; r < 4; ++r)
                fb[e * 64 + ((16 * t + 4 * g + r) ^ se)] = aB[t][r];
        #pragma unroll
        for (int q = 0; q < 2; ++q) {
            const int row = q * 8 + (lane >> 3);
            const int sr  = ((row & 1) << 4) | ((row >> 1) & 3);
            const int c0  = (lane & 7) * 8;
            uint4 o;
            o.x = pk2(fb[row * 64 + ((c0 + 0) ^ sr)], fb[row * 64 + ((c0 + 1) ^ sr)]);
            o.y = pk2(fb[row * 64 + ((c0 + 2) ^ sr)], fb[row * 64 + ((c0 + 3) ^ sr)]);
            o.z = pk2(fb[row * 64 + ((c0 + 4) ^ sr)], fb[row * 64 + ((c0 + 5) ^ sr)]);
            o.w = pk2(fb[row * 64 + ((c0 + 6) ^ sr)], fb[row * 64 + ((c0 + 7) ^ sr)]);
            *(uint4*)((char*)Pb + (size_t)tile * 2048 + q * 1024 + lane * 16) = o;
        }
    }
}

// ============ Bucket sort stage 1: sharded hist / scan / scatter ============
extern "C" __global__ void __launch_bounds__(256)
hist2_kernel(const int* __restrict__ ei, int* __restrict__ cnt2)
{
    const int b  = blockIdx.x;                   // grid must be 2048
    const int i0 = b * E2;
    const int i1 = (i0 + E2 < NE) ? i0 + E2 : NE;
    const int sh = b & (NSH - 1);
    for (int i = i0 + threadIdx.x; i < i1; i += 256)
        atomicAdd(&cnt2[(ei[NE + i] >> GSH) * NSH + sh], 1);
}

extern "C" __global__ void __launch_bounds__(1024)
scanA_kernel(const int* __restrict__ cnt2, int* __restrict__ off2, int* __restrict__ bsum)
{
    __shared__ int sh[1024];
    const int t = threadIdx.x;
    const int i = blockIdx.x * 1024 + t;
    const int v = (i < NSB) ? cnt2[i] : 0;
    sh[t] = v;
    __syncthreads();
    for (int off = 1; off < 1024; off <<= 1) {
        const int u = (t >= off) ? sh[t - off] : 0;
        __syncthreads();
        sh[t] += u;
        __syncthreads();
    }
    if (i < NSB) off2[i] = sh[t] - v;
    if (t == 1023) bsum[blockIdx.x] = sh[1023];
}

extern "C" __global__ void __launch_bounds__(64)
scanB_kernel(int* __restrict__ bsum)
{
    if (threadIdx.x == 0) {
        int run = 0;
        for (int j = 0; j < SCANB; ++j) { const int v = bsum[j]; bsum[j] = run; run += v; }
    }
}

extern "C" __global__ void __launch_bounds__(1024)
scanC_kernel(int* __restrict__ off2, const int* __restrict__ bsum, int* __restrict__ cur2)
{
    const int i = blockIdx.x * 1024 + threadIdx.x;
    if (i < NSB) {
        const int o = off2[i] + bsum[blockIdx.x];
        off2[i] = o;
        cur2[i] = o;
    }
}

extern "C" __global__ void __launch_bounds__(256)
scatter2_kernel(const int* __restrict__ ei, int* __restrict__ cur2,
                unsigned* __restrict__ sedge)
{
    const int b  = blockIdx.x;                   // grid must be 2048
    const int i0 = b * E2;
    const int i1 = (i0 + E2 < NE) ? i0 + E2 : NE;
    const int sh = b & (NSH - 1);
    for (int i = i0 + threadIdx.x; i < i1; i += 256) {
        const int s = ei[i];
        const int d = ei[NE + i];
        const int pos = atomicAdd(&cur2[(d >> GSH) * NSH + sh], 1);
        sedge[pos] = (unsigned)s | ((unsigned)(d & (GSZ - 1)) << 17);
    }
}

// ============ Bucket sort stage 2: per-bucket exact refinement ============
// One block per bucket: its region in sedge is contiguous (bucket-major scan).
// 64-bin LDS counting-sort by dst&63 -> globally exact dst-sorted spair (int2),
// written by ONE block (one XCD) -> L2-merged, no global atomics.
extern "C" __global__ void __launch_bounds__(256)
sort2_kernel(const unsigned* __restrict__ sedge, const int* __restrict__ off2,
             int2* __restrict__ spair)
{
    __shared__ int hist[GSZ], base[GSZ], curs[GSZ];
    const int tid = threadIdx.x;
    const int b   = blockIdx.x;
    const int r0  = off2[b * NSH];
    const int r1  = (b == NB - 1) ? NE : off2[(b + 1) * NSH];

    if (tid < GSZ) hist[tid] = 0;
    __syncthreads();
    for (int i = r0 + tid; i < r1; i += 256)
        atomicAdd(&hist[(sedge[i] >> 17) & (GSZ - 1)], 1);
    __syncthreads();
    if (tid == 0) {
        int run = 0;
        for (int j = 0; j < GSZ; ++j) { base[j] = run; run += hist[j]; }
    }
    __syncthreads();
    if (tid < GSZ) curs[tid] = base[tid];
    __syncthreads();
    for (int i = r0 + tid; i < r1; i += 256) {
        const unsigned pk = sedge[i];
        const int dl = (pk >> 17) & (GSZ - 1);
        const int pos = r0 + atomicAdd(&curs[dl], 1);
        spair[pos] = make_int2((int)(pk & 0x1FFFFu), (b << GSH) | dl);
    }
}

// ============ Edge kernel (sorted): R4-proven register-run accumulation ====
extern "C" __global__ void __launch_bounds__(256, 2)
edge_kernel_sorted(const unsigned short* __restrict__ Pt, const unsigned short* __restrict__ Pb,
                   const float* __restrict__ x, const int2* __restrict__ spair,
                   const float* __restrict__ We2, const float* __restrict__ be2,
                   const float* __restrict__ Winf, const float* __restrict__ binf,
                   float* __restrict__ mi)
{
    __shared__ float fx[4][1024];
    const int tid  = threadIdx.x;
    const int wib  = tid >> 6;
    const int lane = tid & 63;
    const int e = lane & 15, g = lane >> 4;
    float* fb = &fx[wib][0];
    const int se = ((e & 1) << 4) | ((e >> 1) & 3);

    bf16x8 A2[4][2];
    f32x4 b2r[4], wir[4];
    #pragma unroll
    for (int t = 0; t < 4; ++t) {
        #pragma unroll
        for (int ks = 0; ks < 2; ++ks) {
            bf16x8 a;
            #pragma unroll
            for (int j = 0; j < 8; ++j)
                a[j] = f2bf(We2[(32 * ks + 8 * g + j) * 64 + 16 * t + e]);
            A2[t][ks] = a;
        }
        #pragma unroll
        for (int r = 0; r < 4; ++r) {
            b2r[t][r] = be2[16 * t + 4 * g + r];
            wir[t][r] = Winf[16 * t + 4 * g + r];
        }
    }
    const float binf0 = binf[0];

    const int NT     = NE / 16;
    const int nwaves = gridDim.x * 4;
    const int gwid   = blockIdx.x * 4 + wib;
    const int chunk  = (NT + nwaves - 1) / nwaves;
    const int t0 = gwid * chunk;
    const int t1 = (t0 + chunk < NT) ? t0 + chunk : NT;

    float racc  = 0.f;   // running row accumulator, channel = lane
    int   rrow  = -1;    // wave-uniform current node id

    for (int tile = t0; tile < t1; ++tile) {
        const int eid = tile * 16 + e;
        const int2 sd = spair[eid];
        const int sN = sd.x;
        const int dN = sd.y;

        const float dx = x[dN * 3 + 0] - x[sN * 3 + 0];
        const float dy = x[dN * 3 + 1] - x[sN * 3 + 1];
        const float dz = x[dN * 3 + 2] - x[sN * 3 + 2];
        const float dsq = dx * dx + dy * dy + dz * dz;
        const float edis = sigmoidf_(TEMP / (sqrtf(dsq) + 1e-8f));

        bf16x8 B2[2];
        #pragma unroll
        for (int ks = 0; ks < 2; ++ks) {
            const uint4 ut = *(const uint4*)(Pt + (size_t)dN * 64 + 32 * ks + 8 * g);
            const uint4 ub = *(const uint4*)(Pb + (size_t)sN * 64 + 32 * ks + 8 * g);
            bf16x8 bb;
            unsigned tw, bw;
            tw = ut.x; bw = ub.x;
            bb[0] = f2bf(fmaxf(bf2f(tw & 0xffffu) + bf2f(bw & 0xffffu), 0.f));
            bb[1] = f2bf(fmaxf(bf2f(tw >> 16)     + bf2f(bw >> 16),     0.f));
            tw = ut.y; bw = ub.y;
            bb[2] = f2bf(fmaxf(bf2f(tw & 0xffffu) + bf2f(bw & 0xffffu), 0.f));
            bb[3] = f2bf(fmaxf(bf2f(tw >> 16)     + bf2f(bw >> 16),     0.f));
            tw = ut.z; bw = ub.z;
            bb[4] = f2bf(fmaxf(bf2f(tw & 0xffffu) + bf2f(bw & 0xffffu), 0.f));
            bb[5] = f2bf(fmaxf(bf2f(tw >> 16)     + bf2f(bw >> 16),     0.f));
            tw = ut.w; bw = ub.w;
            bb[6] = f2bf(fmaxf(bf2f(tw & 0xffffu) + bf2f(bw & 0xffffu), 0.f));
            bb[7] = f2bf(fmaxf(bf2f(tw >> 16)     + bf2f(bw >> 16),     0.f));
            B2[ks] = bb;
        }

        f32x4 acc2[4];
        #pragma unroll
        for (int t = 0; t < 4; ++t) {
            acc2[t] = b2r[t];
            #pragma unroll
            for (int ks = 0; ks < 2; ++ks)
                acc2[t] = __builtin_amdgcn_mfma_f32_16x16x32_bf16(A2[t][ks], B2[ks], acc2[t], 0, 0, 0);
        }

        float m[4][4];
        float p = 0.f;
        #pragma unroll
        for (int t = 0; t < 4; ++t)
            #pragma unroll
            for (int r = 0; r < 4; ++r) {
                m[t][r] = fmaxf(acc2[t][r], 0.f);
                p = fmaf(m[t][r], wir[t][r], p);
            }
        p += __shfl_xor(p, 16);
        p += __shfl_xor(p, 32);
        const float w = sigmoidf_((p + binf0) * edis);

        #pragma unroll
        for (int t = 0; t < 4; ++t)
            #pragma unroll
            for (int r = 0; r < 4; ++r)
                fb[e * 64 + ((16 * t + 4 * g + r) ^ se)] = m[t][r] * w;

        #pragma unroll
        for (int i = 0; i < 16; ++i) {
            const int row = __builtin_amdgcn_readlane(dN, i);
            const int si = ((i & 1) << 4) | ((i >> 1) & 3);
            const float v = fb[i * 64 + (lane ^ si)];
            if (row != rrow) {
                if (rrow >= 0) atomicAdd(mi + (size_t)rrow * 64 + lane, racc);
                rrow = row; racc = v;
            } else {
                racc += v;
            }
        }
    }
    if (rrow >= 0) atomicAdd(mi + (size_t)rrow * 64 + lane, racc);
}

// ============ Edge kernel (unsorted fallback, small-ws path) ============
extern "C" __global__ void __launch_bounds__(256, 2)
edge_kernel_unsorted(const unsigned short* __restrict__ Pt, const unsigned short* __restrict__ Pb,
                     const float* __restrict__ x, const int* __restrict__ ei,
                     const float* __restrict__ We2, const float* __restrict__ be2,
                     const float* __restrict__ Winf, const float* __restrict__ binf,
                     float* __restrict__ mi)
{
    __shared__ float fx[4][1024];
    const int tid  = threadIdx.x;
    const int wib  = tid >> 6;
    const int lane = tid & 63;
    const int e = lane & 15, g = lane >> 4;
    float* fb = &fx[wib][0];
    const int se = ((e & 1) << 4) | ((e >> 1) & 3);

    bf16x8 A2[4][2];
    f32x4 b2r[4], wir[4];
    #pragma unroll
    for (int t = 0; t < 4; ++t) {
        #pragma unroll
        for (int ks = 0; ks < 2; ++ks) {
            bf16x8 a;
            #pragma unroll
            for (int j = 0; j < 8; ++j)
                a[j] = f2bf(We2[(32 * ks + 8 * g + j) * 64 + 16 * t + e]);
            A2[t][ks] = a;
        }
        #pragma unroll
        for (int r = 0; r < 4; ++r) {
            b2r[t][r] = be2[16 * t + 4 * g + r];
            wir[t][r] = Winf[16 * t + 4 * g + r];
        }
    }
    const float binf0 = binf[0];

    const int gwid = blockIdx.x * 4 + wib;
    const int nw   = gridDim.x * 4;

    for (int tile = gwid; tile < NE / 16; tile += nw) {
        const int eid = tile * 16 + e;
        const int sN = ei[eid];
        const int dN = ei[NE + eid];

        const float dx = x[dN * 3 + 0] - x[sN * 3 + 0];
        const float dy = x[dN * 3 + 1] - x[sN * 3 + 1];
        const float dz = x[dN * 3 + 2] - x[sN * 3 + 2];
        const float dsq = dx * dx + dy * dy + dz * dz;
        const float edis = sigmoidf_(TEMP / (sqrtf(dsq) + 1e-8f));

        bf16x8 B2[2];
        #pragma unroll
        for (int ks = 0; ks < 2; ++ks) {
            const uint4 ut = *(const uint4*)(Pt + (size_t)dN * 64 + 32 * ks + 8 * g);
            const uint4 ub = *(const uint4*)(Pb + (size_t)sN * 64 + 32 * ks + 8 * g);
            bf16x8 bb;
            unsigned tw, bw;
            tw = ut.x; bw = ub.x;
            bb[0] = f2bf(fmaxf(bf2f(tw & 0xffffu) + bf2f(bw & 0xffffu), 0.f));
            bb[1] = f2bf(fmaxf(bf2f(tw >> 16)     + bf2f(bw >> 16),     0.f));
            tw = ut.y; bw = ub.y;
            bb[2] = f2bf(fmaxf(bf2f(tw & 0xffffu) + bf2f(bw & 0xffffu), 0.f));
            bb[3] = f2bf(fmaxf(bf2f(tw >> 16)     + bf2f(bw >> 16),     0.f));
            tw = ut.z; bw = ub.z;
            bb[4] = f2bf(fmaxf(bf2f(tw & 0xffffu) + bf2f(bw & 0xffffu), 0.f));
            bb[5] = f2bf(fmaxf(bf2f(tw >> 16)     + bf2f(bw >> 16),     0.f));
            tw = ut.w; bw = ub.w;
            bb[6] = f2bf(fmaxf(bf2f(tw & 0xffffu) + bf2f(bw & 0xffffu), 0.f));
            bb[7] = f2bf(fmaxf(bf2f(tw >> 16)     + bf2f(bw >> 16),     0.f));
            B2[ks] = bb;
        }

        f32x4 acc2[4];
        #pragma unroll
        for (int t = 0; t < 4; ++t) {
            acc2[t] = b2r[t];
            #pragma unroll
            for (int ks = 0; ks < 2; ++ks)
                acc2[t] = __builtin_amdgcn_mfma_f32_16x16x32_bf16(A2[t][ks], B2[ks], acc2[t], 0, 0, 0);
        }

        float m[4][4];
        float p = 0.f;
        #pragma unroll
        for (int t = 0; t < 4; ++t)
            #pragma unroll
            for (int r = 0; r < 4; ++r) {
                m[t][r] = fmaxf(acc2[t][r], 0.f);
                p = fmaf(m[t][r], wir[t][r], p);
            }
        p += __shfl_xor(p, 16);
        p += __shfl_xor(p, 32);
        const float w = sigmoidf_((p + binf0) * edis);

        #pragma unroll
        for (int t = 0; t < 4; ++t)
            #pragma unroll
            for (int r = 0; r < 4; ++r)
                fb[e * 64 + ((16 * t + 4 * g + r) ^ se)] = m[t][r] * w;

        #pragma unroll
        for (int i = 0; i < 16; ++i) {
            const int row = __shfl(dN, i);
            const int si = ((i & 1) << 4) | ((i >> 1) & 3);
            const float v = fb[i * 64 + (lane ^ si)];
            atomicAdd(mi + (size_t)row * 64 + lane, v);
        }
    }
}

// ============ Node kernel: same B2B MFMA + residual + LayerNorm =============
extern "C" __global__ void __launch_bounds__(256, 2)
node_kernel(const float* __restrict__ h, const float* __restrict__ mi_,
            const float* __restrict__ Wn1, const float* __restrict__ bn1,
            const float* __restrict__ Wn2, const float* __restrict__ bn2,
            const float* __restrict__ lng, const float* __restrict__ lnb,
            float* __restrict__ out)
{
    __shared__ unsigned xlds[4][16 * 32];
    const int tid  = threadIdx.x;
    const int wib  = tid >> 6;
    const int lane = tid & 63;
    const int e = lane & 15, g = lane >> 4;
    unsigned* tb = &xlds[wib][0];
    const int sw = (e & 7) << 2;

    bf16x8 A1[4][4], A2[4][2];
    f32x4 b1r[4], b2r[4], gr[4], br[4];
    #pragma unroll
    for (int t = 0; t < 4; ++t) {
        #pragma unroll
        for (int ks = 0; ks < 4; ++ks) {
            bf16x8 a;
            #pragma unroll
            for (int j = 0; j < 8; ++j)
                a[j] = f2bf(Wn1[(32 * ks + 8 * g + j) * 64 + 16 * t + e]);
            A1[t][ks] = a;
        }
        #pragma unroll
        for (int ks = 0; ks < 2; ++ks) {
            bf16x8 a;
            #pragma unroll
            for (int j = 0; j < 8; ++j)
                a[j] = f2bf(Wn2[(32 * ks + 8 * g + j) * 64 + 16 * t + e]);
            A2[t][ks] = a;
        }
        #pragma unroll
        for (int r = 0; r < 4; ++r) {
            b1r[t][r] = bn1[16 * t + 4 * g + r];
            b2r[t][r] = bn2[16 * t + 4 * g + r];
            gr[t][r]  = lng[16 * t + 4 * g + r];
            br[t][r]  = lnb[16 * t + 4 * g + r];
        }
    }

    const int gwid = blockIdx.x * 4 + wib;
    const int nw   = gridDim.x * 4;

    for (int tile = gwid; tile < NN / 16; tile += nw) {
        const int node = tile * 16 + e;

        bf16x8 B1[4];
        #pragma unroll
        for (int ks = 0; ks < 4; ++ks) {
            const float* srcp = (ks < 2) ? mi_ : h;
            const float4* p = (const float4*)(srcp + (size_t)node * 64 + (ks & 1) * 32 + 8 * g);
            const float4 f0 = p[0], f1 = p[1];
            bf16x8 b;
            b[0] = f2bf(f0.x); b[1] = f2bf(f0.y); b[2] = f2bf(f0.z); b[3] = f2bf(f0.w);
            b[4] = f2bf(f1.x); b[5] = f2bf(f1.y); b[6] = f2bf(f1.z); b[7] = f2bf(f1.w);
            B1[ks] = b;
        }

        f32x4 acc1[4];
        #pragma unroll
        for (int t = 0; t < 4; ++t) {
            acc1[t] = b1r[t];
            #pragma unroll
            for (int ks = 0; ks < 4; ++ks)
                acc1[t] = __builtin_amdgcn_mfma_f32_16x16x32_bf16(A1[t][ks], B1[ks], acc1[t], 0, 0, 0);
        }

        #pragma unroll
        for (int t = 0; t < 4; ++t) {
            const float r0 = fmaxf(acc1[t][0], 0.f), r1 = fmaxf(acc1[t][1], 0.f);
            const float r2 = fmaxf(acc1[t][2], 0.f), r3 = fmaxf(acc1[t][3], 0.f);
            tb[e * 32 + ((8 * t + 2 * g + 0) ^ sw)] = pk2(r0, r1);
            tb[e * 32 + ((8 * t + 2 * g + 1) ^ sw)] = pk2(r2, r3);
        }
        bf16x8 B2[2];
        #pragma unroll
        for (int ks = 0; ks < 2; ++ks) {
            union { uint4 u; bf16x8 b; } cvt;
            cvt.u = *(const uint4*)&tb[e * 32 + ((16 * ks + 4 * g) ^ sw)];
            B2[ks] = cvt.b;
        }

        f32x4 acc2[4];
        #pragma unroll
        for (int t = 0; t < 4; ++t) {
            acc2[t] = b2r[t];
            #pragma unroll
            for (int ks = 0; ks < 2; ++ks)
                acc2[t] = __builtin_amdgcn_mfma_f32_16x16x32_bf16(A2[t][ks], B2[ks], acc2[t], 0, 0, 0);
        }

        float z[4][4];
        float s1 = 0.f, s2 = 0.f;
        #pragma unroll
        for (int t = 0; t < 4; ++t) {
            const float4 hres = *(const float4*)(h + (size_t)node * 64 + 16 * t + 4 * g);
            #pragma unroll
            for (int r = 0; r < 4; ++r) {
                z[t][r] = acc2[t][r] + hres[r];
                s1 += z[t][r];
                s2 = fmaf(z[t][r], z[t][r], s2);
            }
        }
        s1 += __shfl_xor(s1, 16); s1 += __shfl_xor(s1, 32);
        s2 += __shfl_xor(s2, 16); s2 += __shfl_xor(s2, 32);
        const float mu   = s1 * (1.0f / 64.0f);
        const float var  = s2 * (1.0f / 64.0f) - mu * mu;
        const float rstd = rsqrtf(var + LNEPS);

        #pragma unroll
        for (int t = 0; t < 4; ++t) {
            float4 o;
            #pragma unroll
            for (int r = 0; r < 4; ++r)
                o[r] = (z[t][r] - mu) * rstd * gr[t][r] + br[t][r];
            *(float4*)(out + (size_t)node * 64 + 16 * t + 4 * g) = o;
        }
    }
}

extern "C" void kernel_launch(void* const* d_in, const int* in_sizes, int n_in,
                              void* d_out, int out_size, void* d_ws, size_t ws_size,
                              hipStream_t stream)
{
    const float* h    = (const float*)d_in[0];
    const float* x    = (const float*)d_in[1];
    const int*   ei   = (const int*)d_in[2];
    const float* We1  = (const float*)d_in[3];
    const float* be1  = (const float*)d_in[4];
    const float* We2  = (const float*)d_in[5];
    const float* be2  = (const float*)d_in[6];
    const float* Winf = (const float*)d_in[7];
    const float* binf = (const float*)d_in[8];
    const float* Wn1  = (const float*)d_in[9];
    const float* bn1  = (const float*)d_in[10];
    const float* Wn2  = (const float*)d_in[11];
    const float* bn2  = (const float*)d_in[12];
    const float* lng  = (const float*)d_in[13];
    const float* lnb  = (const float*)d_in[14];
    float* out = (float*)d_out;

    const size_t mi_bytes = (size_t)NN * HDIM * sizeof(float);          // 25.6 MB
    const size_t p_bytes  = (size_t)NN * HDIM * sizeof(unsigned short); // 12.8 MB
    const size_t sp_bytes = (size_t)NE * sizeof(int2);                  // 12.8 MB
    const size_t c_bytes  = (size_t)NSB * sizeof(int);                  // ~50 KB
    const size_t bs_bytes = SCANB * sizeof(int);

    // sedge (6.4 MB, packed u32) aliases mi's first bytes: dead before memset(mi)
    const size_t need_sorted = mi_bytes + 2 * p_bytes + sp_bytes + 3 * c_bytes + bs_bytes;

    if (ws_size >= need_sorted) {
        char* ws = (char*)d_ws;
        float*          mi    = (float*)ws;              ws += mi_bytes;
        unsigned short* Pt    = (unsigned short*)ws;     ws += p_bytes;
        unsigned short* Pb    = (unsigned short*)ws;     ws += p_bytes;
        int2*           spair = (int2*)ws;               ws += sp_bytes;
        int*            cnt2  = (int*)ws;                ws += c_bytes;
        int*            off2  = (int*)ws;                ws += c_bytes;
        int*            cur2  = (int*)ws;                ws += c_bytes;
        int*            bsum  = (int*)ws;
        unsigned*       sedge = (unsigned*)mi;           // aliased, dead before memset

        hipMemsetAsync(cnt2, 0, c_bytes, stream);
        hipMemcpyAsync(out + (size_t)NN * HDIM, x, (size_t)NN * 3 * sizeof(float),
                       hipMemcpyDeviceToDevice, stream);

        hist2_kernel<<<2048, 256, 0, stream>>>(ei, cnt2);
        scanA_kernel<<<SCANB, 1024, 0, stream>>>(cnt2, off2, bsum);
        scanB_kernel<<<1, 64, 0, stream>>>(bsum);
        scanC_kernel<<<SCANB, 1024, 0, stream>>>(off2, bsum, cur2);
        scatter2_kernel<<<2048, 256, 0, stream>>>(ei, cur2, sedge);
        sort2_kernel<<<NB, 256, 0, stream>>>(sedge, off2, spair);
        pre_kernel<<<512, 256, 0, stream>>>(h, We1, be1, Pt, Pb);
        hipMemsetAsync(mi, 0, mi_bytes, stream);         // after sort2: frees sedge alias
        edge_kernel_sorted<<<2048, 256, 0, stream>>>(Pt, Pb, x, spair, We2, be2, Winf, binf, mi);
        node_kernel<<<512, 256, 0, stream>>>(h, mi, Wn1, bn1, Wn2, bn2, lng, lnb, out);
    } else {
        float* mi;
        unsigned short* Pt;
        unsigned short* Pb;
        if (ws_size >= mi_bytes + 2 * p_bytes) {
            mi = (float*)d_ws;
            Pt = (unsigned short*)((char*)d_ws + mi_bytes);
            Pb = (unsigned short*)((char*)d_ws + mi_bytes + p_bytes);
        } else {
            mi = out;
            Pt = (unsigned short*)d_ws;
            Pb = (unsigned short*)((char*)d_ws + p_bytes);
        }

        hipMemsetAsync(mi, 0, mi_bytes, stream);
        hipMemcpyAsync(out + (size_t)NN * HDIM, x, (size_t)NN * 3 * sizeof(float),
                       hipMemcpyDeviceToDevice, stream);

        pre_kernel<<<512, 256, 0, stream>>>(h, We1, be1, Pt, Pb);
        edge_kernel_unsorted<<<2048, 256, 0, stream>>>(Pt, Pb, x, ei, We2, be2, Winf, binf, mi);
        node_kernel<<<512, 256, 0, stream>>>(h, mi, Wn1, bn1, Wn2, bn2, lng, lnb, out);
    }
}